// Round 10
// baseline (57.511 us; speedup 1.0000x reference)
//
#include <hip/hip_runtime.h>
#include <math.h>

#define NPTS 16384
#define NB   2
#define RCH  1024               // refs per block (LDS tile), 32 KiB
#define NRC  (NPTS / RCH)       // 16
#define TILES (RCH / 32)        // 32 mfma ref-tiles per block
#define QPB  256                // queries per block: 4 waves * 2 frags * 32
#define NQC  (NPTS / QPB)       // 64
#define TOTQ (NB * NPTS)        // 32768
#define TOTMIN (2 * TOTQ)       // 65536

typedef short bf16x8 __attribute__((ext_vector_type(8)));
typedef float f32x16 __attribute__((ext_vector_type(16)));

// monotone float <-> uint (t can be negative)
__device__ __forceinline__ unsigned ordf(float f) {
    unsigned b = __float_as_uint(f);
    return (b & 0x80000000u) ? ~b : (b | 0x80000000u);
}
__device__ __forceinline__ float deordf(unsigned u) {
    return __uint_as_float((u & 0x80000000u) ? (u ^ 0x80000000u) : ~u);
}
// bf16 round-to-nearest-even
__device__ __forceinline__ unsigned short bfr(float v) {
    unsigned u = __float_as_uint(v);
    u += 0x7FFFu + ((u >> 16) & 1u);
    return (unsigned short)(u >> 16);
}
__device__ __forceinline__ float ubf(unsigned short h) {
    return __uint_as_float(((unsigned)h) << 16);
}

// K-slot assignment (11 of 16 used):
//  k:      0     1     2     3     4     5     6     7  |  8     9    10   11..15
//  A(ref): rhx   rlx   rhx   rhy   rly   rhy   rhz   rlz|  rhz   wh   wl   0
//  B(qry): -qhx  -qhx  -qlx  -qhy  -qhy  -qly  -qhz  -qhz| -qlz  1.0  1.0  0
// => C = 0.5|r|^2 - q.r
__global__ __launch_bounds__(256) void prep_kernel(const float* __restrict__ pred,
                                                   const float* __restrict__ target,
                                                   unsigned short* __restrict__ panel,
                                                   unsigned short* __restrict__ qpack,
                                                   float* __restrict__ wq,
                                                   unsigned* __restrict__ mins) {
    int t = blockIdx.x * 256 + threadIdx.x;      // 0..65535
    int cloud = t >> 15, r = t & 32767, b = r >> 14, i = r & 16383;
    const float* src = cloud ? target : pred;
    float x = src[(b * NPTS + i) * 3 + 0];
    float y = src[(b * NPTS + i) * 3 + 1];
    float zz = src[(b * NPTS + i) * 3 + 2];
    float w = 0.5f * (x * x + y * y + zz * zz);

    unsigned short hx = bfr(x),  lx = bfr(x - ubf(hx));
    unsigned short hy = bfr(y),  ly = bfr(y - ubf(hy));
    unsigned short hz = bfr(zz), lz = bfr(zz - ubf(hz));
    unsigned short hw = bfr(w),  lw = bfr(w - ubf(hw));

    const int slot = cloud * 2 + b;

    // A-panel: ref-major, 32B/ref, LDS-linear
    unsigned short* pp = panel + ((size_t)slot << 18) + (size_t)(i >> 5) * 512 + (size_t)(i & 31) * 8;
    uint4 k0, k1;
    k0.x = hx | ((unsigned)lx << 16);
    k0.y = hx | ((unsigned)hy << 16);
    k0.z = ly | ((unsigned)hy << 16);
    k0.w = hz | ((unsigned)lz << 16);
    *(uint4*)pp = k0;
    k1.x = hz | ((unsigned)hw << 16);
    k1.y = lw;
    k1.z = 0; k1.w = 0;
    *(uint4*)(pp + 256) = k1;

    // B-pack: 32B/query, negated split (sign flip is exact)
    const unsigned short S = 0x8000u, ONE = 0x3F80u;
    unsigned short nhx = hx ^ S, nlx = lx ^ S, nhy = hy ^ S, nly = ly ^ S, nhz = hz ^ S, nlz = lz ^ S;
    unsigned short* qp = qpack + ((size_t)slot << 18) + (size_t)i * 16;
    uint4 qlo, qhi;
    qlo.x = nhx | ((unsigned)nhx << 16);
    qlo.y = nlx | ((unsigned)nhy << 16);
    qlo.z = nhy | ((unsigned)nly << 16);
    qlo.w = nhz | ((unsigned)nhz << 16);
    qhi.x = nlz | ((unsigned)ONE << 16);
    qhi.y = ONE;
    qhi.z = 0; qhi.w = 0;
    *(uint4*)qp = qlo;
    *(uint4*)(qp + 8) = qhi;

    wq[(slot << 14) | i] = w;
    mins[(slot << 14) | i] = 0xFFFFFFFFu;
}

// 2 B-fragments per wave -> only 32 live D regs -> arch VGPRs, no accvgpr traffic.
__global__ __launch_bounds__(256) void nn_min_kernel(const unsigned short* __restrict__ panel,
                                                     const unsigned short* __restrict__ qpack,
                                                     unsigned* __restrict__ mins) {
    __shared__ __attribute__((aligned(16))) unsigned short lds_s[RCH * 16];  // 32 KiB

    const int z = blockIdx.z, b = z & 1, qc = z >> 1, rc = 1 - qc;
    const int tid = threadIdx.x, ln = tid & 63, wv = tid >> 6;

    // ---- stage ref panel chunk -> LDS ----
    const unsigned short* pbase = panel + (((size_t)(rc * 2 + b)) << 18) + (size_t)blockIdx.x * (RCH * 16);
    uint4 st0 = *(const uint4*)(pbase + (0 * 256 + tid) * 8);
    uint4 st1 = *(const uint4*)(pbase + (1 * 256 + tid) * 8);
    uint4 st2 = *(const uint4*)(pbase + (2 * 256 + tid) * 8);
    uint4 st3 = *(const uint4*)(pbase + (3 * 256 + tid) * 8);
    uint4 st4 = *(const uint4*)(pbase + (4 * 256 + tid) * 8);
    uint4 st5 = *(const uint4*)(pbase + (5 * 256 + tid) * 8);
    uint4 st6 = *(const uint4*)(pbase + (6 * 256 + tid) * 8);
    uint4 st7 = *(const uint4*)(pbase + (7 * 256 + tid) * 8);

    // ---- B fragments: 2 query-frags of 32 queries per wave ----
    const int qbase = blockIdx.y * QPB;
    const unsigned short* qb = qpack + (((size_t)(qc * 2 + b)) << 18);
    const int qcol = ln & 31, khalf = (ln >> 5) * 8;
    bf16x8 B0 = *(const bf16x8*)(qb + (size_t)(qbase + (wv * 2 + 0) * 32 + qcol) * 16 + khalf);
    bf16x8 B1 = *(const bf16x8*)(qb + (size_t)(qbase + (wv * 2 + 1) * 32 + qcol) * 16 + khalf);

    *(uint4*)&lds_s[(0 * 256 + tid) * 8] = st0;
    *(uint4*)&lds_s[(1 * 256 + tid) * 8] = st1;
    *(uint4*)&lds_s[(2 * 256 + tid) * 8] = st2;
    *(uint4*)&lds_s[(3 * 256 + tid) * 8] = st3;
    *(uint4*)&lds_s[(4 * 256 + tid) * 8] = st4;
    *(uint4*)&lds_s[(5 * 256 + tid) * 8] = st5;
    *(uint4*)&lds_s[(6 * 256 + tid) * 8] = st6;
    *(uint4*)&lds_s[(7 * 256 + tid) * 8] = st7;
    __syncthreads();

    f32x16 cz = {0.f, 0.f, 0.f, 0.f, 0.f, 0.f, 0.f, 0.f,
                 0.f, 0.f, 0.f, 0.f, 0.f, 0.f, 0.f, 0.f};
    float mA0 = INFINITY, mB0 = INFINITY, mA1 = INFINITY, mB1 = INFINITY;

#define FOLD(d, mA, mB)                                                       \
    mA = fminf(fminf(mA, d[0]), d[1]);   mB = fminf(fminf(mB, d[2]), d[3]);   \
    mA = fminf(fminf(mA, d[4]), d[5]);   mB = fminf(fminf(mB, d[6]), d[7]);   \
    mA = fminf(fminf(mA, d[8]), d[9]);   mB = fminf(fminf(mB, d[10]), d[11]); \
    mA = fminf(fminf(mA, d[12]), d[13]); mB = fminf(fminf(mB, d[14]), d[15]);

    for (int t = 0; t < TILES; ++t) {
        bf16x8 a = *(const bf16x8*)&lds_s[t * 512 + ln * 8];   // ds_read_b128
        f32x16 d0 = __builtin_amdgcn_mfma_f32_32x32x16_bf16(a, B0, cz, 0, 0, 0);
        f32x16 d1 = __builtin_amdgcn_mfma_f32_32x32x16_bf16(a, B1, cz, 0, 0, 0);
        FOLD(d0, mA0, mB0)
        FOLD(d1, mA1, mB1)
    }
#undef FOLD

    unsigned* om = mins + ((size_t)z << 14) + qbase;
    atomicMin(&om[(wv * 2 + 0) * 32 + qcol], ordf(fminf(mA0, mB0)));
    atomicMin(&om[(wv * 2 + 1) * 32 + qcol], ordf(fminf(mA1, mB1)));
}

// d = sqrt(max(0, 2*(0.5|q|^2 + t_min)))
__global__ __launch_bounds__(256) void reduceA_kernel(const unsigned* __restrict__ mins,
                                                      const float* __restrict__ wq,
                                                      float* __restrict__ partials) {
    int base = blockIdx.x * 1024;
    float s = 0.f;
    #pragma unroll
    for (int k = 0; k < 4; ++k) {
        int t = base + k * 256 + threadIdx.x;
        float m = deordf(mins[t]);
        s += sqrtf(fmaxf(0.f, 2.f * (wq[t] + m)));
    }
    #pragma unroll
    for (int off = 32; off; off >>= 1) s += __shfl_down(s, off);
    __shared__ float wsum[4];
    int lane = threadIdx.x & 63, wv = threadIdx.x >> 6;
    if (lane == 0) wsum[wv] = s;
    __syncthreads();
    if (threadIdx.x == 0) partials[blockIdx.x] = wsum[0] + wsum[1] + wsum[2] + wsum[3];
}

__global__ void reduceB_kernel(const float* __restrict__ partials, float* __restrict__ out) {
    float s = partials[threadIdx.x];
    #pragma unroll
    for (int off = 32; off; off >>= 1) s += __shfl_down(s, off);
    if (threadIdx.x == 0) out[0] = s / (float)TOTQ;
}

extern "C" void kernel_launch(void* const* d_in, const int* in_sizes, int n_in,
                              void* d_out, int out_size, void* d_ws, size_t ws_size,
                              hipStream_t stream) {
    const float* pred   = (const float*)d_in[0];
    const float* target = (const float*)d_in[1];
    char* ws = (char*)d_ws;

    unsigned short* panel = (unsigned short*)ws;                              // 2 MiB
    unsigned short* qpack = (unsigned short*)(ws + (size_t)2 * 1024 * 1024);  // 2 MiB
    float*          wq    = (float*)(ws + (size_t)4 * 1024 * 1024);
    unsigned*       mins  = (unsigned*)(ws + (size_t)4 * 1024 * 1024 + 256 * 1024);
    float*       partials = (float*)(ws + (size_t)4 * 1024 * 1024 + 512 * 1024);
    float* out = (float*)d_out;

    prep_kernel<<<TOTMIN / 256, 256, 0, stream>>>(pred, target, panel, qpack, wq, mins);

    dim3 grid(NRC, NQC, 2 * NB);   // 16 x 64 x 4 = 4096 blocks
    nn_min_kernel<<<grid, 256, 0, stream>>>(panel, qpack, mins);

    reduceA_kernel<<<64, 256, 0, stream>>>(mins, wq, partials);
    reduceB_kernel<<<1, 64, 0, stream>>>(partials, out);
}

// Round 11
// 46.268 us; speedup vs baseline: 1.2430x; 1.2430x over previous
//
#include <hip/hip_runtime.h>
#include <math.h>

#define NPTS 16384
#define NB   2
#define RCH  1024               // refs per block (LDS tile), 32 KiB
#define NRC  (NPTS / RCH)       // 16
#define TILES (RCH / 32)        // 32 mfma ref-tiles per block
#define QPB  256                // queries per block: 4 waves * 2 frags * 32
#define NQC  (NPTS / QPB)       // 64
#define TOTQ (NB * NPTS)        // 32768
#define TOTMIN (2 * TOTQ)       // 65536

typedef short bf16x8 __attribute__((ext_vector_type(8)));
typedef float f32x16 __attribute__((ext_vector_type(16)));

// tied-accumulator min3: acc = min(acc, x, y); no result mov
#define MIN3(acc, x, y) \
    asm("v_min3_f32 %0, %0, %1, %2" : "+v"(acc) : "v"(x), "v"(y))

// monotone float <-> uint (t can be negative)
__device__ __forceinline__ unsigned ordf(float f) {
    unsigned b = __float_as_uint(f);
    return (b & 0x80000000u) ? ~b : (b | 0x80000000u);
}
__device__ __forceinline__ float deordf(unsigned u) {
    return __uint_as_float((u & 0x80000000u) ? (u ^ 0x80000000u) : ~u);
}
// bf16 round-to-nearest-even
__device__ __forceinline__ unsigned short bfr(float v) {
    unsigned u = __float_as_uint(v);
    u += 0x7FFFu + ((u >> 16) & 1u);
    return (unsigned short)(u >> 16);
}
__device__ __forceinline__ float ubf(unsigned short h) {
    return __uint_as_float(((unsigned)h) << 16);
}

// K-slot assignment (11 of 16 used):
//  k:      0     1     2     3     4     5     6     7  |  8     9    10   11..15
//  A(ref): rhx   rlx   rhx   rhy   rly   rhy   rhz   rlz|  rhz   wh   wl   0
//  B(qry): -qhx  -qhx  -qlx  -qhy  -qhy  -qly  -qhz  -qhz| -qlz  1.0  1.0  0
// => D = 0.5|r|^2 - q.r  (C = literal 0 in the MFMA)
__global__ __launch_bounds__(256) void prep_kernel(const float* __restrict__ pred,
                                                   const float* __restrict__ target,
                                                   unsigned short* __restrict__ panel,
                                                   unsigned short* __restrict__ qpack,
                                                   float* __restrict__ wq,
                                                   unsigned* __restrict__ mins) {
    int t = blockIdx.x * 256 + threadIdx.x;      // 0..65535
    int cloud = t >> 15, r = t & 32767, b = r >> 14, i = r & 16383;
    const float* src = cloud ? target : pred;
    float x = src[(b * NPTS + i) * 3 + 0];
    float y = src[(b * NPTS + i) * 3 + 1];
    float zz = src[(b * NPTS + i) * 3 + 2];
    float w = 0.5f * (x * x + y * y + zz * zz);

    unsigned short hx = bfr(x),  lx = bfr(x - ubf(hx));
    unsigned short hy = bfr(y),  ly = bfr(y - ubf(hy));
    unsigned short hz = bfr(zz), lz = bfr(zz - ubf(hz));
    unsigned short hw = bfr(w),  lw = bfr(w - ubf(hw));

    const int slot = cloud * 2 + b;

    // A-panel: ref-major, 32B/ref, LDS-linear
    unsigned short* pp = panel + ((size_t)slot << 18) + (size_t)(i >> 5) * 512 + (size_t)(i & 31) * 8;
    uint4 k0, k1;
    k0.x = hx | ((unsigned)lx << 16);
    k0.y = hx | ((unsigned)hy << 16);
    k0.z = ly | ((unsigned)hy << 16);
    k0.w = hz | ((unsigned)lz << 16);
    *(uint4*)pp = k0;
    k1.x = hz | ((unsigned)hw << 16);
    k1.y = lw;
    k1.z = 0; k1.w = 0;
    *(uint4*)(pp + 256) = k1;

    // B-pack: 32B/query, negated split (sign flip is exact)
    const unsigned short S = 0x8000u, ONE = 0x3F80u;
    unsigned short nhx = hx ^ S, nlx = lx ^ S, nhy = hy ^ S, nly = ly ^ S, nhz = hz ^ S, nlz = lz ^ S;
    unsigned short* qp = qpack + ((size_t)slot << 18) + (size_t)i * 16;
    uint4 qlo, qhi;
    qlo.x = nhx | ((unsigned)nhx << 16);
    qlo.y = nlx | ((unsigned)nhy << 16);
    qlo.z = nhy | ((unsigned)nly << 16);
    qlo.w = nhz | ((unsigned)nhz << 16);
    qhi.x = nlz | ((unsigned)ONE << 16);
    qhi.y = ONE;
    qhi.z = 0; qhi.w = 0;
    *(uint4*)qp = qlo;
    *(uint4*)(qp + 8) = qhi;

    wq[(slot << 14) | i] = w;
    mins[(slot << 14) | i] = 0xFFFFFFFFu;
}

__global__ __launch_bounds__(256, 2) void nn_min_kernel(const unsigned short* __restrict__ panel,
                                                        const unsigned short* __restrict__ qpack,
                                                        unsigned* __restrict__ mins) {
    __shared__ __attribute__((aligned(16))) unsigned short lds_s[RCH * 16];  // 32 KiB

    const int z = blockIdx.z, b = z & 1, qc = z >> 1, rc = 1 - qc;
    const int tid = threadIdx.x, ln = tid & 63, wv = tid >> 6;

    // ---- stage ref panel chunk -> LDS ----
    const unsigned short* pbase = panel + (((size_t)(rc * 2 + b)) << 18) + (size_t)blockIdx.x * (RCH * 16);
    uint4 st0 = *(const uint4*)(pbase + (0 * 256 + tid) * 8);
    uint4 st1 = *(const uint4*)(pbase + (1 * 256 + tid) * 8);
    uint4 st2 = *(const uint4*)(pbase + (2 * 256 + tid) * 8);
    uint4 st3 = *(const uint4*)(pbase + (3 * 256 + tid) * 8);
    uint4 st4 = *(const uint4*)(pbase + (4 * 256 + tid) * 8);
    uint4 st5 = *(const uint4*)(pbase + (5 * 256 + tid) * 8);
    uint4 st6 = *(const uint4*)(pbase + (6 * 256 + tid) * 8);
    uint4 st7 = *(const uint4*)(pbase + (7 * 256 + tid) * 8);

    // ---- B fragments: 2 query-frags of 32 queries per wave ----
    const int qbase = blockIdx.y * QPB;
    const unsigned short* qb = qpack + (((size_t)(qc * 2 + b)) << 18);
    const int qcol = ln & 31, khalf = (ln >> 5) * 8;
    bf16x8 B0 = *(const bf16x8*)(qb + (size_t)(qbase + (wv * 2 + 0) * 32 + qcol) * 16 + khalf);
    bf16x8 B1 = *(const bf16x8*)(qb + (size_t)(qbase + (wv * 2 + 1) * 32 + qcol) * 16 + khalf);

    *(uint4*)&lds_s[(0 * 256 + tid) * 8] = st0;
    *(uint4*)&lds_s[(1 * 256 + tid) * 8] = st1;
    *(uint4*)&lds_s[(2 * 256 + tid) * 8] = st2;
    *(uint4*)&lds_s[(3 * 256 + tid) * 8] = st3;
    *(uint4*)&lds_s[(4 * 256 + tid) * 8] = st4;
    *(uint4*)&lds_s[(5 * 256 + tid) * 8] = st5;
    *(uint4*)&lds_s[(6 * 256 + tid) * 8] = st6;
    *(uint4*)&lds_s[(7 * 256 + tid) * 8] = st7;
    __syncthreads();

    float mA0 = INFINITY, mB0 = INFINITY, mA1 = INFINITY, mB1 = INFINITY;

    // prologue: A-fragment for tile 0
    bf16x8 ac = *(const bf16x8*)&lds_s[ln * 8];

    for (int t = 0; t < TILES; ++t) {
        // prefetch next tile's A-fragment; its lgkmcnt wait lands in the NEXT
        // iteration's asm input, hidden under this iteration's folds.
        const int tn = (t + 1 < TILES) ? t + 1 : t;
        bf16x8 an = *(const bf16x8*)&lds_s[tn * 512 + ln * 8];

        f32x16 d0, d1;
        // literal-0 srcC: no zero tuple, no per-MFMA C copy.
        // s_nop 7+3 covers the 8-pass MFMA vdst -> VALU read hazard.
        asm("v_mfma_f32_32x32x16_bf16 %0, %2, %3, 0\n\t"
            "v_mfma_f32_32x32x16_bf16 %1, %2, %4, 0\n\t"
            "s_nop 7\n\t"
            "s_nop 3"
            : "=&v"(d0), "=&v"(d1)
            : "v"(ac), "v"(B0), "v"(B1));

        // 4 independent min3 chains (ILP), tied accumulators, direct subreg reads
        MIN3(mA0, d0[0], d0[1]);   MIN3(mB0, d0[2], d0[3]);
        MIN3(mA0, d0[4], d0[5]);   MIN3(mB0, d0[6], d0[7]);
        MIN3(mA0, d0[8], d0[9]);   MIN3(mB0, d0[10], d0[11]);
        MIN3(mA0, d0[12], d0[13]); MIN3(mB0, d0[14], d0[15]);
        MIN3(mA1, d1[0], d1[1]);   MIN3(mB1, d1[2], d1[3]);
        MIN3(mA1, d1[4], d1[5]);   MIN3(mB1, d1[6], d1[7]);
        MIN3(mA1, d1[8], d1[9]);   MIN3(mB1, d1[10], d1[11]);
        MIN3(mA1, d1[12], d1[13]); MIN3(mB1, d1[14], d1[15]);

        ac = an;
    }

    unsigned* om = mins + ((size_t)z << 14) + qbase;
    atomicMin(&om[(wv * 2 + 0) * 32 + qcol], ordf(fminf(mA0, mB0)));
    atomicMin(&om[(wv * 2 + 1) * 32 + qcol], ordf(fminf(mA1, mB1)));
}

// d = sqrt(max(0, 2*(0.5|q|^2 + t_min)))
__global__ __launch_bounds__(256) void reduceA_kernel(const unsigned* __restrict__ mins,
                                                      const float* __restrict__ wq,
                                                      float* __restrict__ partials) {
    int base = blockIdx.x * 1024;
    float s = 0.f;
    #pragma unroll
    for (int k = 0; k < 4; ++k) {
        int t = base + k * 256 + threadIdx.x;
        float m = deordf(mins[t]);
        s += sqrtf(fmaxf(0.f, 2.f * (wq[t] + m)));
    }
    #pragma unroll
    for (int off = 32; off; off >>= 1) s += __shfl_down(s, off);
    __shared__ float wsum[4];
    int lane = threadIdx.x & 63, wv = threadIdx.x >> 6;
    if (lane == 0) wsum[wv] = s;
    __syncthreads();
    if (threadIdx.x == 0) partials[blockIdx.x] = wsum[0] + wsum[1] + wsum[2] + wsum[3];
}

__global__ void reduceB_kernel(const float* __restrict__ partials, float* __restrict__ out) {
    float s = partials[threadIdx.x];
    #pragma unroll
    for (int off = 32; off; off >>= 1) s += __shfl_down(s, off);
    if (threadIdx.x == 0) out[0] = s / (float)TOTQ;
}

extern "C" void kernel_launch(void* const* d_in, const int* in_sizes, int n_in,
                              void* d_out, int out_size, void* d_ws, size_t ws_size,
                              hipStream_t stream) {
    const float* pred   = (const float*)d_in[0];
    const float* target = (const float*)d_in[1];
    char* ws = (char*)d_ws;

    unsigned short* panel = (unsigned short*)ws;                              // 2 MiB
    unsigned short* qpack = (unsigned short*)(ws + (size_t)2 * 1024 * 1024);  // 2 MiB
    float*          wq    = (float*)(ws + (size_t)4 * 1024 * 1024);
    unsigned*       mins  = (unsigned*)(ws + (size_t)4 * 1024 * 1024 + 256 * 1024);
    float*       partials = (float*)(ws + (size_t)4 * 1024 * 1024 + 512 * 1024);
    float* out = (float*)d_out;

    prep_kernel<<<TOTMIN / 256, 256, 0, stream>>>(pred, target, panel, qpack, wq, mins);

    dim3 grid(NRC, NQC, 2 * NB);   // 16 x 64 x 4 = 4096 blocks
    nn_min_kernel<<<grid, 256, 0, stream>>>(panel, qpack, mins);

    reduceA_kernel<<<64, 256, 0, stream>>>(mins, wq, partials);
    reduceB_kernel<<<1, 64, 0, stream>>>(partials, out);
}

// Round 12
// 44.388 us; speedup vs baseline: 1.2956x; 1.0424x over previous
//
#include <hip/hip_runtime.h>
#include <math.h>

#define NPTS 16384
#define NB   2
#define RCH  1024               // refs per block (LDS tile), 32 KiB
#define NRC  (NPTS / RCH)       // 16
#define TILES (RCH / 32)        // 32 mfma ref-tiles per block
#define QPB  256                // queries per block: 4 waves * 2 frags * 32
#define NQC  (NPTS / QPB)       // 64
#define TOTQ (NB * NPTS)        // 32768
#define TOTMIN (2 * TOTQ)       // 65536

typedef short bf16x8 __attribute__((ext_vector_type(8)));

// monotone float <-> uint (t can be negative)
__device__ __forceinline__ unsigned ordf(float f) {
    unsigned b = __float_as_uint(f);
    return (b & 0x80000000u) ? ~b : (b | 0x80000000u);
}
__device__ __forceinline__ float deordf(unsigned u) {
    return __uint_as_float((u & 0x80000000u) ? (u ^ 0x80000000u) : ~u);
}
// bf16 round-to-nearest-even
__device__ __forceinline__ unsigned short bfr(float v) {
    unsigned u = __float_as_uint(v);
    u += 0x7FFFu + ((u >> 16) & 1u);
    return (unsigned short)(u >> 16);
}
__device__ __forceinline__ float ubf(unsigned short h) {
    return __uint_as_float(((unsigned)h) << 16);
}

// One fused asm unit: 2 MFMAs -> fixed phys regs v[32:63], own wait-state nops,
// all 16 min3 folds inside. No compiler-visible MFMA-result boundary => no
// conservative inter-asm hazard padding.
#define TILE_STEP(ac, B0, B1, mA0, mB0, mA1, mB1)                          \
    asm("v_mfma_f32_32x32x16_bf16 v[32:47], %4, %5, 0\n\t"                 \
        "v_mfma_f32_32x32x16_bf16 v[48:63], %4, %6, 0\n\t"                 \
        "s_nop 7\n\t"                                                      \
        "s_nop 6\n\t"                                                      \
        "v_min3_f32 %0, %0, v32, v33\n\t"                                  \
        "v_min3_f32 %1, %1, v34, v35\n\t"                                  \
        "v_min3_f32 %0, %0, v36, v37\n\t"                                  \
        "v_min3_f32 %1, %1, v38, v39\n\t"                                  \
        "v_min3_f32 %0, %0, v40, v41\n\t"                                  \
        "v_min3_f32 %1, %1, v42, v43\n\t"                                  \
        "v_min3_f32 %0, %0, v44, v45\n\t"                                  \
        "v_min3_f32 %1, %1, v46, v47\n\t"                                  \
        "v_min3_f32 %2, %2, v48, v49\n\t"                                  \
        "v_min3_f32 %3, %3, v50, v51\n\t"                                  \
        "v_min3_f32 %2, %2, v52, v53\n\t"                                  \
        "v_min3_f32 %3, %3, v54, v55\n\t"                                  \
        "v_min3_f32 %2, %2, v56, v57\n\t"                                  \
        "v_min3_f32 %3, %3, v58, v59\n\t"                                  \
        "v_min3_f32 %2, %2, v60, v61\n\t"                                  \
        "v_min3_f32 %3, %3, v62, v63\n\t"                                  \
        : "+v"(mA0), "+v"(mB0), "+v"(mA1), "+v"(mB1)                       \
        : "v"(ac), "v"(B0), "v"(B1)                                        \
        : "v32","v33","v34","v35","v36","v37","v38","v39",                 \
          "v40","v41","v42","v43","v44","v45","v46","v47",                 \
          "v48","v49","v50","v51","v52","v53","v54","v55",                 \
          "v56","v57","v58","v59","v60","v61","v62","v63")

// K-slot assignment (11 of 16 used):
//  k:      0     1     2     3     4     5     6     7  |  8     9    10   11..15
//  A(ref): rhx   rlx   rhx   rhy   rly   rhy   rhz   rlz|  rhz   wh   wl   0
//  B(qry): -qhx  -qhx  -qlx  -qhy  -qhy  -qly  -qhz  -qhz| -qlz  1.0  1.0  0
// => D = 0.5|r|^2 - q.r  (C = literal 0 in the MFMA)
__global__ __launch_bounds__(256) void prep_kernel(const float* __restrict__ pred,
                                                   const float* __restrict__ target,
                                                   unsigned short* __restrict__ panel,
                                                   unsigned short* __restrict__ qpack,
                                                   float* __restrict__ wq,
                                                   unsigned* __restrict__ mins) {
    int t = blockIdx.x * 256 + threadIdx.x;      // 0..65535
    int cloud = t >> 15, r = t & 32767, b = r >> 14, i = r & 16383;
    const float* src = cloud ? target : pred;
    float x = src[(b * NPTS + i) * 3 + 0];
    float y = src[(b * NPTS + i) * 3 + 1];
    float zz = src[(b * NPTS + i) * 3 + 2];
    float w = 0.5f * (x * x + y * y + zz * zz);

    unsigned short hx = bfr(x),  lx = bfr(x - ubf(hx));
    unsigned short hy = bfr(y),  ly = bfr(y - ubf(hy));
    unsigned short hz = bfr(zz), lz = bfr(zz - ubf(hz));
    unsigned short hw = bfr(w),  lw = bfr(w - ubf(hw));

    const int slot = cloud * 2 + b;

    // A-panel: ref-major, 32B/ref, LDS-linear
    unsigned short* pp = panel + ((size_t)slot << 18) + (size_t)(i >> 5) * 512 + (size_t)(i & 31) * 8;
    uint4 k0, k1;
    k0.x = hx | ((unsigned)lx << 16);
    k0.y = hx | ((unsigned)hy << 16);
    k0.z = ly | ((unsigned)hy << 16);
    k0.w = hz | ((unsigned)lz << 16);
    *(uint4*)pp = k0;
    k1.x = hz | ((unsigned)hw << 16);
    k1.y = lw;
    k1.z = 0; k1.w = 0;
    *(uint4*)(pp + 256) = k1;

    // B-pack: 32B/query, negated split (sign flip is exact)
    const unsigned short S = 0x8000u, ONE = 0x3F80u;
    unsigned short nhx = hx ^ S, nlx = lx ^ S, nhy = hy ^ S, nly = ly ^ S, nhz = hz ^ S, nlz = lz ^ S;
    unsigned short* qp = qpack + ((size_t)slot << 18) + (size_t)i * 16;
    uint4 qlo, qhi;
    qlo.x = nhx | ((unsigned)nhx << 16);
    qlo.y = nlx | ((unsigned)nhy << 16);
    qlo.z = nhy | ((unsigned)nly << 16);
    qlo.w = nhz | ((unsigned)nhz << 16);
    qhi.x = nlz | ((unsigned)ONE << 16);
    qhi.y = ONE;
    qhi.z = 0; qhi.w = 0;
    *(uint4*)qp = qlo;
    *(uint4*)(qp + 8) = qhi;

    wq[(slot << 14) | i] = w;
    mins[(slot << 14) | i] = 0xFFFFFFFFu;
}

__global__ __launch_bounds__(256, 4) void nn_min_kernel(const unsigned short* __restrict__ panel,
                                                        const unsigned short* __restrict__ qpack,
                                                        unsigned* __restrict__ mins) {
    __shared__ __attribute__((aligned(16))) unsigned short lds_s[RCH * 16];  // 32 KiB

    const int z = blockIdx.z, b = z & 1, qc = z >> 1, rc = 1 - qc;
    const int tid = threadIdx.x, ln = tid & 63, wv = tid >> 6;

    // ---- stage ref panel chunk -> LDS ----
    const unsigned short* pbase = panel + (((size_t)(rc * 2 + b)) << 18) + (size_t)blockIdx.x * (RCH * 16);
    uint4 st0 = *(const uint4*)(pbase + (0 * 256 + tid) * 8);
    uint4 st1 = *(const uint4*)(pbase + (1 * 256 + tid) * 8);
    uint4 st2 = *(const uint4*)(pbase + (2 * 256 + tid) * 8);
    uint4 st3 = *(const uint4*)(pbase + (3 * 256 + tid) * 8);
    uint4 st4 = *(const uint4*)(pbase + (4 * 256 + tid) * 8);
    uint4 st5 = *(const uint4*)(pbase + (5 * 256 + tid) * 8);
    uint4 st6 = *(const uint4*)(pbase + (6 * 256 + tid) * 8);
    uint4 st7 = *(const uint4*)(pbase + (7 * 256 + tid) * 8);

    // ---- B fragments: 2 query-frags of 32 queries per wave ----
    const int qbase = blockIdx.y * QPB;
    const unsigned short* qb = qpack + (((size_t)(qc * 2 + b)) << 18);
    const int qcol = ln & 31, khalf = (ln >> 5) * 8;
    bf16x8 B0 = *(const bf16x8*)(qb + (size_t)(qbase + (wv * 2 + 0) * 32 + qcol) * 16 + khalf);
    bf16x8 B1 = *(const bf16x8*)(qb + (size_t)(qbase + (wv * 2 + 1) * 32 + qcol) * 16 + khalf);

    *(uint4*)&lds_s[(0 * 256 + tid) * 8] = st0;
    *(uint4*)&lds_s[(1 * 256 + tid) * 8] = st1;
    *(uint4*)&lds_s[(2 * 256 + tid) * 8] = st2;
    *(uint4*)&lds_s[(3 * 256 + tid) * 8] = st3;
    *(uint4*)&lds_s[(4 * 256 + tid) * 8] = st4;
    *(uint4*)&lds_s[(5 * 256 + tid) * 8] = st5;
    *(uint4*)&lds_s[(6 * 256 + tid) * 8] = st6;
    *(uint4*)&lds_s[(7 * 256 + tid) * 8] = st7;
    __syncthreads();

    float mA0 = INFINITY, mB0 = INFINITY, mA1 = INFINITY, mB1 = INFINITY;

    // 2-deep rotation, hand-unrolled x2 so buffer swap is free (no v_movs)
    bf16x8 a0 = *(const bf16x8*)&lds_s[0 * 512 + ln * 8];
    bf16x8 a1 = *(const bf16x8*)&lds_s[1 * 512 + ln * 8];

    #pragma unroll
    for (int t = 0; t < TILES; t += 2) {
        bf16x8 n0, n1;
        if (t + 2 < TILES) {
            n0 = *(const bf16x8*)&lds_s[(t + 2) * 512 + ln * 8];
            n1 = *(const bf16x8*)&lds_s[(t + 3) * 512 + ln * 8];
        }
        TILE_STEP(a0, B0, B1, mA0, mB0, mA1, mB1);
        TILE_STEP(a1, B0, B1, mA0, mB0, mA1, mB1);
        a0 = n0; a1 = n1;
    }

    unsigned* om = mins + ((size_t)z << 14) + qbase;
    atomicMin(&om[(wv * 2 + 0) * 32 + qcol], ordf(fminf(mA0, mB0)));
    atomicMin(&om[(wv * 2 + 1) * 32 + qcol], ordf(fminf(mA1, mB1)));
}

// d = sqrt(max(0, 2*(0.5|q|^2 + t_min)))
__global__ __launch_bounds__(256) void reduceA_kernel(const unsigned* __restrict__ mins,
                                                      const float* __restrict__ wq,
                                                      float* __restrict__ partials) {
    int base = blockIdx.x * 1024;
    float s = 0.f;
    #pragma unroll
    for (int k = 0; k < 4; ++k) {
        int t = base + k * 256 + threadIdx.x;
        float m = deordf(mins[t]);
        s += sqrtf(fmaxf(0.f, 2.f * (wq[t] + m)));
    }
    #pragma unroll
    for (int off = 32; off; off >>= 1) s += __shfl_down(s, off);
    __shared__ float wsum[4];
    int lane = threadIdx.x & 63, wv = threadIdx.x >> 6;
    if (lane == 0) wsum[wv] = s;
    __syncthreads();
    if (threadIdx.x == 0) partials[blockIdx.x] = wsum[0] + wsum[1] + wsum[2] + wsum[3];
}

__global__ void reduceB_kernel(const float* __restrict__ partials, float* __restrict__ out) {
    float s = partials[threadIdx.x];
    #pragma unroll
    for (int off = 32; off; off >>= 1) s += __shfl_down(s, off);
    if (threadIdx.x == 0) out[0] = s / (float)TOTQ;
}

extern "C" void kernel_launch(void* const* d_in, const int* in_sizes, int n_in,
                              void* d_out, int out_size, void* d_ws, size_t ws_size,
                              hipStream_t stream) {
    const float* pred   = (const float*)d_in[0];
    const float* target = (const float*)d_in[1];
    char* ws = (char*)d_ws;

    unsigned short* panel = (unsigned short*)ws;                              // 2 MiB
    unsigned short* qpack = (unsigned short*)(ws + (size_t)2 * 1024 * 1024);  // 2 MiB
    float*          wq    = (float*)(ws + (size_t)4 * 1024 * 1024);
    unsigned*       mins  = (unsigned*)(ws + (size_t)4 * 1024 * 1024 + 256 * 1024);
    float*       partials = (float*)(ws + (size_t)4 * 1024 * 1024 + 512 * 1024);
    float* out = (float*)d_out;

    prep_kernel<<<TOTMIN / 256, 256, 0, stream>>>(pred, target, panel, qpack, wq, mins);

    dim3 grid(NRC, NQC, 2 * NB);   // 16 x 64 x 4 = 4096 blocks
    nn_min_kernel<<<grid, 256, 0, stream>>>(panel, qpack, mins);

    reduceA_kernel<<<64, 256, 0, stream>>>(mins, wq, partials);
    reduceB_kernel<<<1, 64, 0, stream>>>(partials, out);
}